// Round 2
// 788.186 us; speedup vs baseline: 1.2011x; 1.2011x over previous
//
#include <hip/hip_runtime.h>
#include <stdint.h>

// GMHCA: B=4, Lq=1024, Lkv=2048, NH=16, D=64.
// I/O fp32; internal compute bf16 MFMA.
// d_out (fp32) = [ out 4*1024*1024 | attn 64*1024*2048 ].

typedef unsigned short ushort_t;
typedef __bf16 bf16x8 __attribute__((ext_vector_type(8)));
typedef float  f32x4  __attribute__((ext_vector_type(4)));
typedef unsigned short u16x8 __attribute__((ext_vector_type(8)));

__device__ __forceinline__ float bf2f(ushort_t h) {
  union { unsigned int u; float f; } c; c.u = ((unsigned int)h) << 16; return c.f;
}
__device__ __forceinline__ ushort_t f2bf(float f) {
  union { float f; unsigned int u; } c; c.f = f;
  unsigned int u = c.u;
  return (ushort_t)((u + 0x7FFFu + ((u >> 16) & 1u)) >> 16);  // RNE
}

// Async global->LDS, 16B per lane. LDS dest must be linear (base + lane*16).
__device__ __forceinline__ void gl16(const void* gp, void* lp) {
  __builtin_amdgcn_global_load_lds(
      (__attribute__((address_space(1))) void*)(void*)gp,
      (__attribute__((address_space(3))) void*)lp, 16, 0, 0);
}

// ---------------------------------------------------------------------------
// fp32 -> bf16 elementwise (8 elems/thread, exact-size grid)
// ---------------------------------------------------------------------------
__global__ void cvt_bf16(const float* __restrict__ in, ushort_t* __restrict__ out) {
  long i = ((long)blockIdx.x * 256 + threadIdx.x) * 8;
  f32x4 a = *(const f32x4*)(&in[i]);
  f32x4 b = *(const f32x4*)(&in[i + 4]);
  u16x8 v;
#pragma unroll
  for (int e = 0; e < 4; e++) { v[e] = f2bf(a[e]); v[4 + e] = f2bf(b[e]); }
  *(u16x8*)(&out[i]) = v;
}

// ---------------------------------------------------------------------------
// Weight convert+transpose: out_bf16[c*ldo + r] = (bf16) in_f32[r*ldi + c]
// ---------------------------------------------------------------------------
__global__ void wconv_t(const float* __restrict__ in, ushort_t* __restrict__ out,
                        int ldi, int ldo) {
  __shared__ ushort_t t[32][33];
  const int r0 = blockIdx.y * 32, c0 = blockIdx.x * 32;
  const int tx = threadIdx.x & 31, ty = threadIdx.x >> 5;
#pragma unroll
  for (int i = 0; i < 4; i++) {
    int r = ty + i * 8;
    t[r][tx] = f2bf(in[(long)(r0 + r) * ldi + c0 + tx]);
  }
  __syncthreads();
#pragma unroll
  for (int i = 0; i < 4; i++) {
    int c = ty + i * 8;
    out[(long)(c0 + c) * ldo + r0 + tx] = t[tx][c];
  }
}

// bf16 transpose (for V^T), batched over blockIdx.z
__global__ void transpose_bf16(const ushort_t* __restrict__ in,
                               ushort_t* __restrict__ out, int ldi, int ldo,
                               long sbi, long sbo) {
  __shared__ ushort_t t[32][33];
  in += (long)blockIdx.z * sbi;
  out += (long)blockIdx.z * sbo;
  const int r0 = blockIdx.y * 32, c0 = blockIdx.x * 32;
  const int tx = threadIdx.x & 31, ty = threadIdx.x >> 5;
#pragma unroll
  for (int i = 0; i < 4; i++) {
    int r = ty + i * 8;
    t[r][tx] = in[(long)(r0 + r) * ldi + c0 + tx];
  }
  __syncthreads();
#pragma unroll
  for (int i = 0; i < 4; i++) {
    int c = ty + i * 8;
    out[(long)(c0 + c) * ldo + r0 + tx] = t[tx][c];
  }
}

// ---------------------------------------------------------------------------
// C[M,N] = A[M,K] @ Bt[N,K]^T (+bias). A,Bt bf16. C fp32 (CF32) or bf16.
// 128x128 tile, BK=64, 4 waves, 16x16x32 bf16 MFMA.
// m97 structure: global_load_lds(16B) staging, linear LDS dest,
// inverse-swizzled global source + swizzled ds_read (conflict-free).
// Swizzle: 16B-granule index g ^= (row & 7) within each 128B row.
// ---------------------------------------------------------------------------
template <bool CF32>
__global__ __launch_bounds__(256, 2) void gemm_bt(
    const ushort_t* __restrict__ A, const ushort_t* __restrict__ Bt,
    void* __restrict__ Cp, const float* __restrict__ bias,
    int K, int lda, int ldb, int ldc) {
  __shared__ ushort_t As[128 * 64];
  __shared__ ushort_t Bs[128 * 64];
  const int tid  = threadIdx.x;
  const int wave = tid >> 6, lane = tid & 63;
  const int quad = lane >> 4, l15 = lane & 15;
  const int wr = wave >> 1, wc = wave & 1;
  const long m0 = (long)blockIdx.x * 128;
  const long n0 = (long)blockIdx.y * 128;
  // staging geometry: dest byte o = i*4096 + tid*16 (wave-uniform base + lane*16)
  const int srow = tid >> 3;                              // row within 32-row band
  const int scol = (((tid & 7) ^ (srow & 7)) & 7) << 3;   // swizzled source col (elems)

  f32x4 acc[4][4];
#pragma unroll
  for (int i = 0; i < 4; i++)
#pragma unroll
    for (int j = 0; j < 4; j++) acc[i][j] = (f32x4)0.0f;

  for (int k0 = 0; k0 < K; k0 += 64) {
    __syncthreads();
#pragma unroll
    for (int i = 0; i < 4; i++) {
      int row = i * 32 + srow;
      gl16(&A [(m0 + row) * lda + k0 + scol], (char*)As + i * 4096 + tid * 16);
      gl16(&Bt[(n0 + row) * ldb + k0 + scol], (char*)Bs + i * 4096 + tid * 16);
    }
    __syncthreads();  // drains vmcnt(0) -> tile ready
#pragma unroll
    for (int ks = 0; ks < 64; ks += 32) {
      const int gb = ks >> 3;  // granule base: 0 or 4
      bf16x8 af[4], bfr[4];
#pragma unroll
      for (int i = 0; i < 4; i++) {
        int row = wr * 64 + i * 16 + l15;
        af[i] = *(const bf16x8*)((const char*)As + (row << 7) +
                                 ((((gb + quad) ^ (row & 7)) & 7) << 4));
      }
#pragma unroll
      for (int j = 0; j < 4; j++) {
        int row = wc * 64 + j * 16 + l15;
        bfr[j] = *(const bf16x8*)((const char*)Bs + (row << 7) +
                                  ((((gb + quad) ^ (row & 7)) & 7) << 4));
      }
#pragma unroll
      for (int i = 0; i < 4; i++)
#pragma unroll
        for (int j = 0; j < 4; j++)
          acc[i][j] = __builtin_amdgcn_mfma_f32_16x16x32_bf16(af[i], bfr[j], acc[i][j], 0, 0, 0);
    }
  }
  // C/D layout: col = lane&15, row = quad*4 + reg (m89/m91-verified)
#pragma unroll
  for (int i = 0; i < 4; i++) {
    long row = m0 + wr * 64 + i * 16 + quad * 4;
#pragma unroll
    for (int j = 0; j < 4; j++) {
      long col = n0 + wc * 64 + j * 16 + l15;
      float bv = bias ? bias[col] : 0.0f;
#pragma unroll
      for (int r = 0; r < 4; r++) {
        float v = acc[i][j][r] + bv;
        if (CF32) ((float*)Cp)[(row + r) * ldc + col] = v;
        else      ((ushort_t*)Cp)[(row + r) * ldc + col] = f2bf(v);
      }
    }
  }
}

// ---------------------------------------------------------------------------
// Fused attention. Block = (b*16+h, 64 q rows), 4 waves. Two-pass exact
// softmax in exp2 domain. K/V staged via global_load_lds with source-side
// XOR swizzle (linear LDS dest). P stored to global DIRECTLY from QK^T
// registers (fp32, 64B segments) -- removes the LDS roundtrip + 3rd barrier.
// Ps (bf16) kept only for the PV A-fragment (same-wave dep, no barrier).
// ---------------------------------------------------------------------------
#define LQK 72    // Qs pad (reg-staged, read-few)
#define LPJ 136   // Ps pad

__global__ __launch_bounds__(256, 2) void attn_kernel(
    const ushort_t* __restrict__ qb,  // [B*1024, 1024] bf16
    const ushort_t* __restrict__ kb,  // [B*2048, 1024] bf16 (K proj)
    const ushort_t* __restrict__ vt,  // [B*16*64, 2048] bf16 (V^T)
    float* __restrict__ pout,         // [64, 1024, 2048] fp32
    ushort_t* __restrict__ ao) {      // [B*1024, 1024] bf16
  __shared__ ushort_t Qs[64 * LQK];
  __shared__ ushort_t Ks[128 * 64];   // linear, swizzled content
  __shared__ ushort_t Vs[64 * 128];   // linear, swizzled content
  __shared__ ushort_t Ps[64 * LPJ];

  const int tid  = threadIdx.x;
  const int wave = tid >> 6, lane = tid & 63;
  const int quad = lane >> 4, l15 = lane & 15;
  const int bn = blockIdx.x;  // 0..63
  const int b = bn >> 4, h = bn & 15;
  const int q0 = blockIdx.y * 64;
  const float SL2E = 0.125f * 1.44269504088896340736f;  // scale * log2(e)

  // staging geometry
  const int srow = tid >> 3;                              // K tile (128B rows)
  const int scol = (((tid & 7) ^ (srow & 7)) & 7) << 3;
  const int vrs  = tid >> 4;                              // V tile (256B rows)
  const int vcs  = (((tid & 15) ^ vrs) & 15) << 3;

  {  // stage Q tile [64 x 64] (reg path, padded LDS)
    int r = tid >> 3, c = (tid & 7) * 8;
#pragma unroll
    for (int p = 0; p < 2; p++) {
      int row = p * 32 + r;
      *(u16x8*)(&Qs[row * LQK + c]) =
          *(const u16x8*)(&qb[((long)(b * 1024 + q0 + row)) * 1024 + h * 64 + c]);
    }
  }
  __syncthreads();
  bf16x8 aq0 = *(const bf16x8*)(&Qs[(wave * 16 + l15) * LQK + quad * 8]);
  bf16x8 aq1 = *(const bf16x8*)(&Qs[(wave * 16 + l15) * LQK + 32 + quad * 8]);

  float m[4], l[4];
#pragma unroll
  for (int r = 0; r < 4; r++) { m[r] = -1e30f; l[r] = 0.0f; }

  // ---- pass 1: row max + denom ----
  for (int t0 = 0; t0 < 2048; t0 += 128) {
    __syncthreads();
#pragma unroll
    for (int i = 0; i < 4; i++) {
      int row = i * 32 + srow;
      gl16(&kb[((long)(b * 2048 + t0 + row)) * 1024 + h * 64 + scol],
           (char*)Ks + i * 4096 + tid * 16);
    }
    __syncthreads();
    float u[8][4];
#pragma unroll
    for (int ni = 0; ni < 8; ni++) {
      int krow = ni * 16 + l15;
      bf16x8 b0 = *(const bf16x8*)((const char*)Ks + (krow << 7) +
                                   (((quad ^ (krow & 7)) & 7) << 4));
      bf16x8 b1 = *(const bf16x8*)((const char*)Ks + (krow << 7) +
                                   ((((4 + quad) ^ (krow & 7)) & 7) << 4));
      f32x4 s = (f32x4)0.0f;
      s = __builtin_amdgcn_mfma_f32_16x16x32_bf16(aq0, b0, s, 0, 0, 0);
      s = __builtin_amdgcn_mfma_f32_16x16x32_bf16(aq1, b1, s, 0, 0, 0);
#pragma unroll
      for (int r = 0; r < 4; r++) u[ni][r] = s[r] * SL2E;
    }
#pragma unroll
    for (int r = 0; r < 4; r++) {
      float tm = u[0][r];
#pragma unroll
      for (int ni = 1; ni < 8; ni++) tm = fmaxf(tm, u[ni][r]);
      tm = fmaxf(tm, __shfl_xor(tm, 1));
      tm = fmaxf(tm, __shfl_xor(tm, 2));
      tm = fmaxf(tm, __shfl_xor(tm, 4));
      tm = fmaxf(tm, __shfl_xor(tm, 8));
      float mn = fmaxf(m[r], tm);
      float ts = 0.0f;
#pragma unroll
      for (int ni = 0; ni < 8; ni++) ts += __builtin_amdgcn_exp2f(u[ni][r] - mn);
      ts += __shfl_xor(ts, 1);
      ts += __shfl_xor(ts, 2);
      ts += __shfl_xor(ts, 4);
      ts += __shfl_xor(ts, 8);
      l[r] = l[r] * __builtin_amdgcn_exp2f(m[r] - mn) + ts;
      m[r] = mn;
    }
  }

  float rl[4];
#pragma unroll
  for (int r = 0; r < 4; r++) rl[r] = 1.0f / l[r];

  f32x4 o[4];
#pragma unroll
  for (int d = 0; d < 4; d++) o[d] = (f32x4)0.0f;

  // ---- pass 2: recompute S, direct fp32 P store, fused PV ----
  const long pbase = ((long)bn * 1024 + q0 + wave * 16 + quad * 4) * 2048 + l15;
  for (int t0 = 0; t0 < 2048; t0 += 128) {
    __syncthreads();
#pragma unroll
    for (int i = 0; i < 4; i++) {
      int row = i * 32 + srow;
      gl16(&kb[((long)(b * 2048 + t0 + row)) * 1024 + h * 64 + scol],
           (char*)Ks + i * 4096 + tid * 16);
      int vr = i * 16 + vrs;
      gl16(&vt[((long)(bn * 64 + vr)) * 2048 + t0 + vcs],
           (char*)Vs + i * 4096 + tid * 16);
    }
    __syncthreads();
#pragma unroll
    for (int ni = 0; ni < 8; ni++) {
      int krow = ni * 16 + l15;
      bf16x8 b0 = *(const bf16x8*)((const char*)Ks + (krow << 7) +
                                   (((quad ^ (krow & 7)) & 7) << 4));
      bf16x8 b1 = *(const bf16x8*)((const char*)Ks + (krow << 7) +
                                   ((((4 + quad) ^ (krow & 7)) & 7) << 4));
      f32x4 s = (f32x4)0.0f;
      s = __builtin_amdgcn_mfma_f32_16x16x32_bf16(aq0, b0, s, 0, 0, 0);
      s = __builtin_amdgcn_mfma_f32_16x16x32_bf16(aq1, b1, s, 0, 0, 0);
#pragma unroll
      for (int r = 0; r < 4; r++) {
        float pv = __builtin_amdgcn_exp2f(s[r] * SL2E - m[r]) * rl[r];
        pout[pbase + (long)r * 2048 + t0 + ni * 16] = pv;   // exact fp32 P
        Ps[(wave * 16 + quad * 4 + r) * LPJ + ni * 16 + l15] = f2bf(pv);
      }
    }
    // fused PV: O[16q x 64d] per wave (Ps dep is same-wave -> no barrier)
#pragma unroll
    for (int js = 0; js < 128; js += 32) {
      const int gb = js >> 3;  // 0,4,8,12
      bf16x8 ap = *(const bf16x8*)(&Ps[(wave * 16 + l15) * LPJ + js + quad * 8]);
#pragma unroll
      for (int d = 0; d < 4; d++) {
        int vrow = d * 16 + l15;
        bf16x8 bv = *(const bf16x8*)((const char*)Vs + (vrow << 8) +
                                     ((((gb + quad) ^ l15) & 15) << 4));
        o[d] = __builtin_amdgcn_mfma_f32_16x16x32_bf16(ap, bv, o[d], 0, 0, 0);
      }
    }
  }
#pragma unroll
  for (int d = 0; d < 4; d++) {
#pragma unroll
    for (int r = 0; r < 4; r++) {
      int row = q0 + wave * 16 + quad * 4 + r;
      int col = h * 64 + d * 16 + l15;
      ao[((long)(b * 1024 + row)) * 1024 + col] = f2bf(o[d][r]);
    }
  }
}

// ---------------------------------------------------------------------------
extern "C" void kernel_launch(void* const* d_in, const int* in_sizes, int n_in,
                              void* d_out, int out_size, void* d_ws, size_t ws_size,
                              hipStream_t stream) {
  (void)in_sizes; (void)n_in; (void)out_size; (void)ws_size;
  const float* query   = (const float*)d_in[0];  // [4,1024,1024]
  const float* context = (const float*)d_in[1];  // [4,2048,1024]
  const float* Wq      = (const float*)d_in[2];  // [1024,1024]
  const float* Wkv     = (const float*)d_in[3];  // [1024,2048]
  const float* Wo      = (const float*)d_in[4];  // [1024,1024]
  const float* bo      = (const float*)d_in[5];  // [1024]
  float* out = (float*)d_out;

  // ws layout (64 MB), manual lifetimes:
  //  0MB WoT(2) | 2MB WqT(2) | 4MB WkvT(4) | 8MB qbuf(8) | 16MB kbuf(16)
  // 32MB cbf(16) -> vt(16)   | 48MB qbf(8) -> vbuf(16) -> ao(8)
  char* ws = (char*)d_ws;
  ushort_t* WoT  = (ushort_t*)(ws);
  ushort_t* WqT  = (ushort_t*)(ws + (2ll  << 20));
  ushort_t* WkvT = (ushort_t*)(ws + (4ll  << 20));
  ushort_t* qbuf = (ushort_t*)(ws + (8ll  << 20));
  ushort_t* kbuf = (ushort_t*)(ws + (16ll << 20));
  ushort_t* cbf  = (ushort_t*)(ws + (32ll << 20));
  ushort_t* vt   = (ushort_t*)(ws + (32ll << 20));  // alias cbf (dead after V gemm)
  ushort_t* qbf  = (ushort_t*)(ws + (48ll << 20));
  ushort_t* vbuf = (ushort_t*)(ws + (48ll << 20));  // alias qbf (dead after Q gemm)
  ushort_t* ao   = (ushort_t*)(ws + (48ll << 20));  // alias vbuf (dead after V^T)

  // weight convert+transpose -> bf16 [out,in]
  wconv_t<<<dim3(32, 32), 256, 0, stream>>>(Wq, WqT, 1024, 1024);
  wconv_t<<<dim3(64, 32), 256, 0, stream>>>(Wkv, WkvT, 2048, 1024);
  wconv_t<<<dim3(32, 32), 256, 0, stream>>>(Wo, WoT, 1024, 1024);

  // activations -> bf16 once (removes fp32-A re-read+convert from gemms)
  cvt_bf16<<<2048, 256, 0, stream>>>(query, qbf);
  cvt_bf16<<<4096, 256, 0, stream>>>(context, cbf);

  // projections (bf16 A, global_load_lds staging)
  gemm_bt<false><<<dim3(32, 8), 256, 0, stream>>>(
      qbf, WqT, qbuf, nullptr, 1024, 1024, 1024, 1024);
  gemm_bt<false><<<dim3(64, 8), 256, 0, stream>>>(
      cbf, WkvT, kbuf, nullptr, 1024, 1024, 1024, 1024);
  gemm_bt<false><<<dim3(64, 8), 256, 0, stream>>>(
      cbf, WkvT + 1024ll * 1024, vbuf, nullptr, 1024, 1024, 1024, 1024);

  // V^T per batch (batched into one launch): vt[(b*16+h)*64+d][j]
  transpose_bf16<<<dim3(32, 64, 4), 256, 0, stream>>>(
      vbuf, vt, 1024, 2048, 2048ll * 1024, 1024ll * 2048);

  // fused attention: P (fp32) -> d_out[4M..], head outputs -> ao
  attn_kernel<<<dim3(64, 16), 256, 0, stream>>>(qbuf, kbuf, vt, out + 4194304, ao);

  // output projection + bias -> d_out[0..4M)
  gemm_bt<true><<<dim3(32, 8), 256, 0, stream>>>(
      ao, WoT, out, bo, 1024, 1024, 1024, 1024);
}